// Round 22
// baseline (256.583 us; speedup 1.0000x reference)
//
#include <hip/hip_runtime.h>
#include <hip/hip_bf16.h>

#define M_TOK 2048
#define K_DIM 1024
#define E_NUM 8
#define DFF   2816
#define TOPK  2
#define NROWS (M_TOK*TOPK)   // 4096 routed rows
#define KSPLIT 4
#define DSLICE (DFF/KSPLIT)          // 704
#define KT2    (DSLICE/64)           // 11
#define KT1    (K_DIM/64)            // 16

typedef __bf16 bf16;
typedef __bf16 bf16x8 __attribute__((ext_vector_type(8)));
typedef __bf16 bf16x4 __attribute__((ext_vector_type(4)));
typedef float  f32x4  __attribute__((ext_vector_type(4)));

__device__ __forceinline__ void gload_lds16(const void* g, void* l) {
    __builtin_amdgcn_global_load_lds(
        (const __attribute__((address_space(1))) void*)g,
        (__attribute__((address_space(3))) void*)l, 16, 0, 0);
}

// ---------------------------------------------------------------------------
// Zero d_out (grid-stride f32x4).
// ---------------------------------------------------------------------------
__global__ __launch_bounds__(256)
void zero_kernel(float* __restrict__ p, int n4)
{
    int i = blockIdx.x * 256 + threadIdx.x;
    int stride = gridDim.x * 256;
    f32x4 z = (f32x4){0.f, 0.f, 0.f, 0.f};
    for (; i < n4; i += stride) ((f32x4*)p)[i] = z;
}

// ---------------------------------------------------------------------------
// Routing (verified since round 2).
// ---------------------------------------------------------------------------
__global__ __launch_bounds__(512)
void route_kernel(const int* __restrict__ ids,
                  const float* __restrict__ tw,
                  int* __restrict__ counts, int* __restrict__ offs,
                  int* __restrict__ row_token, float* __restrict__ row_wgt)
{
    const int e    = threadIdx.x >> 6;
    const int lane = threadIdx.x & 63;
    __shared__ int scnt[E_NUM];

    int cnt = 0;
    for (int i0 = 0; i0 < NROWS; i0 += 64) {
        int id = ids[i0 + lane];
        cnt += __popcll(__ballot(id == e));
    }
    if (lane == 0) scnt[e] = cnt;
    __syncthreads();
    int base = 0;
    for (int j = 0; j < e; ++j) base += scnt[j];
    if (lane == 0) { counts[e] = cnt; offs[e] = base; }

    const unsigned long long ltmask = (1ull << lane) - 1ull;
    int pos = base;
    for (int i0 = 0; i0 < NROWS; i0 += 64) {
        int i = i0 + lane;
        int id = ids[i];
        unsigned long long m = __ballot(id == e);
        if (id == e) {
            int rank = __popcll(m & ltmask);
            row_token[pos + rank] = i >> 1;
            row_wgt[pos + rank]   = tw[i];
        }
        pos += __popcll(m);
    }
}

// ---------------------------------------------------------------------------
// Gather routed rows of X and cast to bf16 (A operand; 8 MB, ~4us).
// ---------------------------------------------------------------------------
__global__ __launch_bounds__(256)
void gather_cast_kernel(const float* __restrict__ X, const int* __restrict__ row_token,
                        bf16* __restrict__ Ag)
{
    const int row = blockIdx.x;
    const int tok = row_token[row];
    f32x4 a = ((const f32x4*)(X + (size_t)tok * K_DIM))[threadIdx.x];
    bf16x4 v;
    #pragma unroll
    for (int j = 0; j < 4; ++j) v[j] = (bf16)a[j];
    ((bf16x4*)(Ag + (size_t)row * K_DIM))[threadIdx.x] = v;
}

// ---------------------------------------------------------------------------
// GEMM1 + silu_and_mul — r15 measured-best compute path (~117us), with a 9th
// grid z-slice (z==E_NUM) whose 704 blocks cast w2 -> w2b bf16 concurrently.
// gemm1 is latency-bound at 26% HBM, so the ~25us of cast HBM traffic hides
// under it; stream order guarantees w2b completes before gemm2 launches.
// ---------------------------------------------------------------------------
__global__ __launch_bounds__(256, 2)
void gemm1_kernel(const bf16* __restrict__ Ag, const float* __restrict__ w1,
                  const float* __restrict__ w2, bf16* __restrict__ w2b,
                  const int* __restrict__ counts, const int* __restrict__ offs,
                  bf16* __restrict__ act)
{
    if (blockIdx.z == E_NUM) {
        // w2 cast slice: 704 blocks x 256 threads x 16 iters x 8 elems.
        long i = ((long)blockIdx.y * 44 + blockIdx.x) * 256 + threadIdx.x;
        const long stride = (long)44 * 16 * 256;
        const long n8 = (long)E_NUM * K_DIM * DFF / 8;
        for (; i < n8; i += stride) {
            f32x4 a = ((const f32x4*)w2)[2*i];
            f32x4 b = ((const f32x4*)w2)[2*i + 1];
            bf16x8 v;
            #pragma unroll
            for (int j = 0; j < 4; ++j) { v[j] = (bf16)a[j]; v[j+4] = (bf16)b[j]; }
            ((bf16x8*)w2b)[i] = v;
        }
        return;
    }

    const int e  = blockIdx.z;
    const int rt = blockIdx.y;
    const int ct = blockIdx.x;              // 0..43
    const int n  = counts[e];
    const int r0 = rt * 256;
    if (r0 >= n) return;
    const int base = offs[e];

    __shared__ __align__(16) bf16  As[256*64];   // 32 KB
    __shared__ __align__(16) float Bs[128*64];   // 32 KB
    bf16x8* Asv = (bf16x8*)As;              // 8 units / row
    f32x4*  BsF = (f32x4*)Bs;               // 16 units / row

    const int t    = threadIdx.x;
    const int lane = t & 63, wv = t >> 6;

    const int rlowA = lane >> 3;
    const int cgA   = (lane & 7) ^ rlowA;
    const bf16* aPtr[8]; bf16* aLds[8];
    #pragma unroll
    for (int i = 0; i < 8; ++i) {
        int r = wv*64 + i*8 + rlowA;        // 0..255
        aPtr[i] = Ag + (size_t)(base + r0 + r) * K_DIM + cgA*8;
        aLds[i] = As + (wv*64 + i*8)*64;
    }

    const int rB  = t >> 4;                 // 0..15
    const int cgB = (t & 15) ^ rB;
    const float* bGate = w1 + ((size_t)e*(2*DFF) + ct*64 + rB) * K_DIM + cgB*4;
    const float* bUp   = w1 + ((size_t)e*(2*DFF) + DFF + ct*64 + rB) * K_DIM + cgB*4;
    float* bLdsW = Bs + wv*256;

    const int wr = wv >> 1, wc = wv & 1;
    const int l15 = lane & 15, lq = lane >> 4;

    f32x4 accG[8][2], accU[8][2];
    #pragma unroll
    for (int m = 0; m < 8; ++m)
        #pragma unroll
        for (int nn = 0; nn < 2; ++nn) {
            accG[m][nn] = (f32x4){0.f,0.f,0.f,0.f};
            accU[m][nn] = (f32x4){0.f,0.f,0.f,0.f};
        }

#define G1_STAGE(KT_) do { \
    _Pragma("unroll") for (int i = 0; i < 8; ++i) \
        gload_lds16(aPtr[i] + (KT_)*64, aLds[i]); \
    _Pragma("unroll") for (int q = 0; q < 4; ++q) { \
        gload_lds16(bGate + (size_t)q*16*K_DIM + (KT_)*64, bLdsW + q*1024); \
        gload_lds16(bUp   + (size_t)q*16*K_DIM + (KT_)*64, bLdsW + (q+4)*1024); \
    } } while (0)

#define G1_CVT8(DST_, ROW_) do { \
    f32x4 lo_ = BsF[(ROW_)*16 + (g0 ^ l15)]; \
    f32x4 hi_ = BsF[(ROW_)*16 + ((g0+1) ^ l15)]; \
    _Pragma("unroll") for (int j = 0; j < 4; ++j) { \
        DST_[j] = (bf16)lo_[j]; DST_[j+4] = (bf16)hi_[j]; } \
    } while (0)

#define G1_COMPUTE() do { \
    _Pragma("unroll") for (int ks = 0; ks < 2; ++ks) { \
        const int g0 = 8*ks + 2*lq; \
        bf16x8 bg[2], bu[2]; \
        _Pragma("unroll") for (int nn = 0; nn < 2; ++nn) { \
            int frg = wc*32 + nn*16 + l15; \
            G1_CVT8(bg[nn], frg); \
            int fru = 64 + wc*32 + nn*16 + l15; \
            G1_CVT8(bu[nn], fru); \
        } \
        _Pragma("unroll") for (int m = 0; m < 8; ++m) { \
            int fr = wr*128 + m*16 + l15; \
            bf16x8 af = Asv[fr*8 + ((ks*4 + lq) ^ (fr & 7))]; \
            _Pragma("unroll") for (int nn = 0; nn < 2; ++nn) { \
                accG[m][nn] = __builtin_amdgcn_mfma_f32_16x16x32_bf16(af, bg[nn], accG[m][nn], 0, 0, 0); \
                accU[m][nn] = __builtin_amdgcn_mfma_f32_16x16x32_bf16(af, bu[nn], accU[m][nn], 0, 0, 0); \
            } \
        } \
    } } while (0)

    G1_STAGE(0);
    for (int kt = 0; kt < KT1; ++kt) {
        __syncthreads();                    // drain vmcnt + barrier
        G1_COMPUTE();
        if (kt + 1 < KT1) { __syncthreads(); G1_STAGE(kt + 1); }
    }

    #pragma unroll
    for (int m = 0; m < 8; ++m)
        #pragma unroll
        for (int nn = 0; nn < 2; ++nn)
            #pragma unroll
            for (int r = 0; r < 4; ++r) {
                int rl = wr*128 + m*16 + lq*4 + r;
                int grow = r0 + rl;
                if (grow < n) {
                    float g = accG[m][nn][r];
                    float u = accU[m][nn][r];
                    float a = (g / (1.f + __expf(-g))) * u;
                    int col = ct*64 + wc*32 + nn*16 + l15;
                    act[(size_t)(base + grow) * DFF + col] = (bf16)a;
                }
            }
#undef G1_STAGE
#undef G1_CVT8
#undef G1_COMPUTE
}

// ---------------------------------------------------------------------------
// GEMM2 — round-11 all-bf16 form (measured ~70-80us there): 128x128 tile,
// KSPLIT=4, A=act(bf16) + B=w2b(bf16) both gload_lds, 32KB LDS total,
// launch_bounds(256,4) -> ~4-5 blocks/CU. Atomic scatter epilogue.
// ---------------------------------------------------------------------------
__global__ __launch_bounds__(256, 4)
void gemm2_kernel(const bf16* __restrict__ act, const bf16* __restrict__ w2b,
                  const int* __restrict__ counts, const int* __restrict__ offs,
                  const int* __restrict__ row_token, const float* __restrict__ row_wgt,
                  float* __restrict__ out)
{
    const int e   = blockIdx.z;
    const int rt  = blockIdx.y;
    const int ct  = blockIdx.x >> 2;          // 0..7 : 128 out cols
    const int ksp = blockIdx.x & 3;           // DFF quarter
    const int n   = counts[e];
    const int r0  = rt * 128;
    if (r0 >= n) return;
    const int base = offs[e];

    __shared__ __align__(16) bf16 As[128*64];   // 16 KB
    __shared__ __align__(16) bf16 Bs[128*64];   // 16 KB
    bf16x8* Asv = (bf16x8*)As;
    bf16x8* Bsv = (bf16x8*)Bs;

    const int t    = threadIdx.x;
    const int lane = t & 63, wv = t >> 6;
    const int rlow = lane >> 3;
    const int cg   = (lane & 7) ^ rlow;

    const bf16* aPtr[4];
    const bf16* bPtr[4];
    bf16* aLds[4]; bf16* bLds[4];
    #pragma unroll
    for (int i = 0; i < 4; ++i) {
        int r = wv*32 + i*8 + rlow;
        aPtr[i] = act + (size_t)(base + r0 + r) * DFF + ksp*DSLICE + cg*8;
        bPtr[i] = w2b + ((size_t)e*K_DIM + ct*128 + r) * DFF + ksp*DSLICE + cg*8;
        aLds[i] = As + (wv*32 + i*8)*64;
        bLds[i] = Bs + (wv*32 + i*8)*64;
    }

    const int wr = wv >> 1, wc = wv & 1;
    const int l15 = lane & 15, lq = lane >> 4;

    f32x4 acc[4][4];
    #pragma unroll
    for (int m = 0; m < 4; ++m)
        #pragma unroll
        for (int nn = 0; nn < 4; ++nn) acc[m][nn] = (f32x4){0.f,0.f,0.f,0.f};

#define G2_STAGE(KT_) do { \
    _Pragma("unroll") for (int i = 0; i < 4; ++i) { \
        gload_lds16(aPtr[i] + (KT_)*64, aLds[i]); \
        gload_lds16(bPtr[i] + (KT_)*64, bLds[i]); \
    } } while (0)

#define G2_COMPUTE() do { \
    _Pragma("unroll") for (int ks = 0; ks < 2; ++ks) { \
        bf16x8 af[4], bf[4]; \
        _Pragma("unroll") for (int m = 0; m < 4; ++m) { \
            int fr = wr*64 + m*16 + l15; \
            af[m] = Asv[fr*8 + ((ks*4 + lq) ^ (fr & 7))]; \
        } \
        _Pragma("unroll") for (int nn = 0; nn < 4; ++nn) { \
            int fr = wc*64 + nn*16 + l15; \
            bf[nn] = Bsv[fr*8 + ((ks*4 + lq) ^ (fr & 7))]; \
        } \
        _Pragma("unroll") for (int m = 0; m < 4; ++m) \
            _Pragma("unroll") for (int nn = 0; nn < 4; ++nn) \
                acc[m][nn] = __builtin_amdgcn_mfma_f32_16x16x32_bf16(af[m], bf[nn], acc[m][nn], 0, 0, 0); \
    } } while (0)

    G2_STAGE(0);
    for (int kt = 0; kt < KT2; ++kt) {
        __syncthreads();
        G2_COMPUTE();
        if (kt + 1 < KT2) { __syncthreads(); G2_STAGE(kt + 1); }
    }

    #pragma unroll
    for (int m = 0; m < 4; ++m)
        #pragma unroll
        for (int nn = 0; nn < 4; ++nn)
            #pragma unroll
            for (int r = 0; r < 4; ++r) {
                int rl = wr*64 + m*16 + lq*4 + r;
                int grow = r0 + rl;
                if (grow < n) {
                    int idx = base + grow;
                    int tok   = row_token[idx];
                    float wgt = row_wgt[idx];
                    int col = ct*128 + wc*64 + nn*16 + l15;
                    atomicAdd(out + (size_t)tok * K_DIM + col, wgt * acc[m][nn][r]);
                }
            }
#undef G2_STAGE
#undef G2_COMPUTE
}

// ---------------------------------------------------------------------------
extern "C" void kernel_launch(void* const* d_in, const int* in_sizes, int n_in,
                              void* d_out, int out_size, void* d_ws, size_t ws_size,
                              hipStream_t stream)
{
    const float* X   = (const float*)d_in[0];
    const float* w1  = (const float*)d_in[1];
    const float* w2  = (const float*)d_in[2];
    const float* tw  = (const float*)d_in[3];
    const int*   ids = (const int*)d_in[4];
    float* out = (float*)d_out;

    // ws layout: act | row_token | row_wgt | counts | offs | Ag | w2b | pad
    char* p = (char*)d_ws;
    bf16*  act       = (bf16*)p;   p += (size_t)NROWS * DFF * 2;
    int*   row_token = (int*)p;    p += (size_t)NROWS * 4;
    float* row_wgt   = (float*)p;  p += (size_t)NROWS * 4;
    int*   counts    = (int*)p;    p += 32;
    int*   offs      = (int*)p;    p += 32;
    bf16*  Ag        = (bf16*)p;   p += (size_t)NROWS * K_DIM * 2;
    bf16*  w2b       = (bf16*)p;   p += (size_t)E_NUM * K_DIM * DFF * 2;
    p += (1u << 20);               // 1 MB pad for benign A-row overreads
    (void)p; (void)ws_size;        // ~80 MB needed; ws >= 162 MB verified

    zero_kernel<<<512, 256, 0, stream>>>(out, out_size / 4);
    route_kernel<<<1, 512, 0, stream>>>(ids, tw, counts, offs, row_token, row_wgt);
    gather_cast_kernel<<<NROWS, 256, 0, stream>>>(X, row_token, Ag);
    // z = 0..7: expert GEMM1 tiles; z = 8: w2->bf16 cast slice (hidden).
    gemm1_kernel<<<dim3(DFF/64, NROWS/256, E_NUM + 1), 256, 0, stream>>>(Ag, w1, w2, w2b, counts, offs, act);
    gemm2_kernel<<<dim3((K_DIM/128)*KSPLIT, NROWS/128, E_NUM), 256, 0, stream>>>(act, w2b, counts, offs, row_token, row_wgt, out);
}

// Round 23
// 246.688 us; speedup vs baseline: 1.0401x; 1.0401x over previous
//
#include <hip/hip_runtime.h>
#include <hip/hip_bf16.h>

#define M_TOK 2048
#define K_DIM 1024
#define E_NUM 8
#define DFF   2816
#define TOPK  2
#define NROWS (M_TOK*TOPK)   // 4096 routed rows
#define KSPLIT 4
#define DSLICE (DFF/KSPLIT)          // 704
#define KT2    (DSLICE/64)           // 11
#define KT1    (K_DIM/64)            // 16

typedef __bf16 bf16;
typedef __bf16 bf16x8 __attribute__((ext_vector_type(8)));
typedef __bf16 bf16x4 __attribute__((ext_vector_type(4)));
typedef float  f32x4  __attribute__((ext_vector_type(4)));

__device__ __forceinline__ void gload_lds16(const void* g, void* l) {
    __builtin_amdgcn_global_load_lds(
        (const __attribute__((address_space(1))) void*)g,
        (__attribute__((address_space(3))) void*)l, 16, 0, 0);
}

// ---------------------------------------------------------------------------
// Fused zero(d_out) + routing (form verified rounds 16-20).
// Block 0 routes; blocks >=1 zero the output.
// ---------------------------------------------------------------------------
__global__ __launch_bounds__(512)
void route_zero_kernel(const int* __restrict__ ids,
                       const float* __restrict__ tw,
                       int* __restrict__ counts, int* __restrict__ offs,
                       int* __restrict__ row_token, float* __restrict__ row_wgt,
                       float* __restrict__ out, int n4)
{
    if (blockIdx.x != 0) {
        int i = (blockIdx.x - 1) * 512 + threadIdx.x;
        int stride = (gridDim.x - 1) * 512;
        f32x4 z = (f32x4){0.f, 0.f, 0.f, 0.f};
        for (; i < n4; i += stride) ((f32x4*)out)[i] = z;
        return;
    }
    const int e    = threadIdx.x >> 6;
    const int lane = threadIdx.x & 63;
    __shared__ int scnt[E_NUM];

    int cnt = 0;
    for (int i0 = 0; i0 < NROWS; i0 += 64) {
        int id = ids[i0 + lane];
        cnt += __popcll(__ballot(id == e));
    }
    if (lane == 0) scnt[e] = cnt;
    __syncthreads();
    int base = 0;
    for (int j = 0; j < e; ++j) base += scnt[j];
    if (lane == 0) { counts[e] = cnt; offs[e] = base; }

    const unsigned long long ltmask = (1ull << lane) - 1ull;
    int pos = base;
    for (int i0 = 0; i0 < NROWS; i0 += 64) {
        int i = i0 + lane;
        int id = ids[i];
        unsigned long long m = __ballot(id == e);
        if (id == e) {
            int rank = __popcll(m & ltmask);
            row_token[pos + rank] = i >> 1;
            row_wgt[pos + rank]   = tw[i];
        }
        pos += __popcll(m);
    }
}

// ---------------------------------------------------------------------------
// Gather routed rows of X and cast to bf16 (A operand; 8 MB, ~4us).
// ---------------------------------------------------------------------------
__global__ __launch_bounds__(256)
void gather_cast_kernel(const float* __restrict__ X, const int* __restrict__ row_token,
                        bf16* __restrict__ Ag)
{
    const int row = blockIdx.x;
    const int tok = row_token[row];
    f32x4 a = ((const f32x4*)(X + (size_t)tok * K_DIM))[threadIdx.x];
    bf16x4 v;
    #pragma unroll
    for (int j = 0; j < 4; ++j) v[j] = (bf16)a[j];
    ((bf16x4*)(Ag + (size_t)row * K_DIM))[threadIdx.x] = v;
}

// ---------------------------------------------------------------------------
// GEMM1 + silu_and_mul — round-15 measured best (~117us).
// M-TILE 256. A: [256][64] bf16 (32KB) gload_lds, law chunk^(r&7) (src-swz).
// B: [128][64] f32 (32KB) gload_lds, fused f32->bf16 on the LDS->reg read.
// 2-phase schedule: [bar] COMPUTE [bar] STAGE(next).
// ---------------------------------------------------------------------------
__global__ __launch_bounds__(256, 2)
void gemm1_kernel(const bf16* __restrict__ Ag, const float* __restrict__ w1,
                  const int* __restrict__ counts, const int* __restrict__ offs,
                  bf16* __restrict__ act)
{
    const int e  = blockIdx.z;
    const int rt = blockIdx.y;
    const int ct = blockIdx.x;              // 0..43
    const int n  = counts[e];
    const int r0 = rt * 256;
    if (r0 >= n) return;
    const int base = offs[e];

    __shared__ __align__(16) bf16  As[256*64];   // 32 KB
    __shared__ __align__(16) float Bs[128*64];   // 32 KB
    bf16x8* Asv = (bf16x8*)As;              // 8 units / row
    f32x4*  BsF = (f32x4*)Bs;               // 16 units / row

    const int t    = threadIdx.x;
    const int lane = t & 63, wv = t >> 6;

    const int rlowA = lane >> 3;
    const int cgA   = (lane & 7) ^ rlowA;
    const bf16* aPtr[8]; bf16* aLds[8];
    #pragma unroll
    for (int i = 0; i < 8; ++i) {
        int r = wv*64 + i*8 + rlowA;        // 0..255
        aPtr[i] = Ag + (size_t)(base + r0 + r) * K_DIM + cgA*8;
        aLds[i] = As + (wv*64 + i*8)*64;
    }

    const int rB  = t >> 4;                 // 0..15
    const int cgB = (t & 15) ^ rB;
    const float* bGate = w1 + ((size_t)e*(2*DFF) + ct*64 + rB) * K_DIM + cgB*4;
    const float* bUp   = w1 + ((size_t)e*(2*DFF) + DFF + ct*64 + rB) * K_DIM + cgB*4;
    float* bLdsW = Bs + wv*256;

    const int wr = wv >> 1, wc = wv & 1;
    const int l15 = lane & 15, lq = lane >> 4;

    f32x4 accG[8][2], accU[8][2];
    #pragma unroll
    for (int m = 0; m < 8; ++m)
        #pragma unroll
        for (int nn = 0; nn < 2; ++nn) {
            accG[m][nn] = (f32x4){0.f,0.f,0.f,0.f};
            accU[m][nn] = (f32x4){0.f,0.f,0.f,0.f};
        }

#define G1_STAGE(KT_) do { \
    _Pragma("unroll") for (int i = 0; i < 8; ++i) \
        gload_lds16(aPtr[i] + (KT_)*64, aLds[i]); \
    _Pragma("unroll") for (int q = 0; q < 4; ++q) { \
        gload_lds16(bGate + (size_t)q*16*K_DIM + (KT_)*64, bLdsW + q*1024); \
        gload_lds16(bUp   + (size_t)q*16*K_DIM + (KT_)*64, bLdsW + (q+4)*1024); \
    } } while (0)

#define G1_CVT8(DST_, ROW_) do { \
    f32x4 lo_ = BsF[(ROW_)*16 + (g0 ^ l15)]; \
    f32x4 hi_ = BsF[(ROW_)*16 + ((g0+1) ^ l15)]; \
    _Pragma("unroll") for (int j = 0; j < 4; ++j) { \
        DST_[j] = (bf16)lo_[j]; DST_[j+4] = (bf16)hi_[j]; } \
    } while (0)

#define G1_COMPUTE() do { \
    _Pragma("unroll") for (int ks = 0; ks < 2; ++ks) { \
        const int g0 = 8*ks + 2*lq; \
        bf16x8 bg[2], bu[2]; \
        _Pragma("unroll") for (int nn = 0; nn < 2; ++nn) { \
            int frg = wc*32 + nn*16 + l15; \
            G1_CVT8(bg[nn], frg); \
            int fru = 64 + wc*32 + nn*16 + l15; \
            G1_CVT8(bu[nn], fru); \
        } \
        _Pragma("unroll") for (int m = 0; m < 8; ++m) { \
            int fr = wr*128 + m*16 + l15; \
            bf16x8 af = Asv[fr*8 + ((ks*4 + lq) ^ (fr & 7))]; \
            _Pragma("unroll") for (int nn = 0; nn < 2; ++nn) { \
                accG[m][nn] = __builtin_amdgcn_mfma_f32_16x16x32_bf16(af, bg[nn], accG[m][nn], 0, 0, 0); \
                accU[m][nn] = __builtin_amdgcn_mfma_f32_16x16x32_bf16(af, bu[nn], accU[m][nn], 0, 0, 0); \
            } \
        } \
    } } while (0)

    G1_STAGE(0);
    for (int kt = 0; kt < KT1; ++kt) {
        __syncthreads();                    // drain vmcnt + barrier
        G1_COMPUTE();
        if (kt + 1 < KT1) { __syncthreads(); G1_STAGE(kt + 1); }
    }

    // epilogue: act = silu(gate) * up  (C/D: col=lane&15, row=(lane>>4)*4+r)
    #pragma unroll
    for (int m = 0; m < 8; ++m)
        #pragma unroll
        for (int nn = 0; nn < 2; ++nn)
            #pragma unroll
            for (int r = 0; r < 4; ++r) {
                int rl = wr*128 + m*16 + lq*4 + r;
                int grow = r0 + rl;
                if (grow < n) {
                    float g = accG[m][nn][r];
                    float u = accU[m][nn][r];
                    float a = (g / (1.f + __expf(-g))) * u;
                    int col = ct*64 + wc*32 + nn*16 + l15;
                    act[(size_t)(base + grow) * DFF + col] = (bf16)a;
                }
            }
#undef G1_STAGE
#undef G1_CVT8
#undef G1_COMPUTE
}

// ---------------------------------------------------------------------------
// GEMM2 — round-15/12 measured best (~117us): 128x128 tile, KSPLIT=4,
// 48KB LDS (3 blocks/CU). A = act (bf16); B = w2 (f32, fused cvt on read);
// atomic scatter epilogue (<=2 commutative adds per output element).
// ---------------------------------------------------------------------------
__global__ __launch_bounds__(256, 2)
void gemm2_kernel(const bf16* __restrict__ act, const float* __restrict__ w2,
                  const int* __restrict__ counts, const int* __restrict__ offs,
                  const int* __restrict__ row_token, const float* __restrict__ row_wgt,
                  float* __restrict__ out)
{
    const int e   = blockIdx.z;
    const int rt  = blockIdx.y;
    const int ct  = blockIdx.x >> 2;          // 0..7 : 128 out cols
    const int ksp = blockIdx.x & 3;           // DFF quarter
    const int n   = counts[e];
    const int r0  = rt * 128;
    if (r0 >= n) return;
    const int base = offs[e];

    __shared__ __align__(16) bf16  As[128*64];   // 16 KB
    __shared__ __align__(16) float Bs[128*64];   // 32 KB
    bf16x8* Asv = (bf16x8*)As;
    f32x4*  BsF = (f32x4*)Bs;

    const int t    = threadIdx.x;
    const int lane = t & 63, wv = t >> 6;

    const int rlowA = lane >> 3;
    const int cgA   = (lane & 7) ^ rlowA;
    const bf16* aPtr[4]; bf16* aLds[4];
    #pragma unroll
    for (int i = 0; i < 4; ++i) {
        int r = wv*32 + i*8 + rlowA;
        aPtr[i] = act + (size_t)(base + r0 + r) * DFF + ksp*DSLICE + cgA*8;
        aLds[i] = As + (wv*32 + i*8)*64;
    }

    const int rB  = t >> 4;
    const int cgB = (t & 15) ^ rB;
    const float* bBase = w2 + ((size_t)e*K_DIM + ct*128 + rB) * DFF + ksp*DSLICE + cgB*4;
    float* bLdsW = Bs + wv*256;

    const int wr = wv >> 1, wc = wv & 1;
    const int l15 = lane & 15, lq = lane >> 4;

    f32x4 acc[4][4];
    #pragma unroll
    for (int m = 0; m < 4; ++m)
        #pragma unroll
        for (int nn = 0; nn < 4; ++nn) acc[m][nn] = (f32x4){0.f,0.f,0.f,0.f};

#define G2_STAGE(KT_) do { \
    _Pragma("unroll") for (int i = 0; i < 4; ++i) \
        gload_lds16(aPtr[i] + (KT_)*64, aLds[i]); \
    _Pragma("unroll") for (int q = 0; q < 8; ++q) \
        gload_lds16(bBase + (size_t)q*16*DFF + (KT_)*64, bLdsW + q*1024); \
    } while (0)

#define G2_CVT8(DST_, ROW_) do { \
    f32x4 lo_ = BsF[(ROW_)*16 + (g0 ^ l15)]; \
    f32x4 hi_ = BsF[(ROW_)*16 + ((g0+1) ^ l15)]; \
    _Pragma("unroll") for (int j = 0; j < 4; ++j) { \
        DST_[j] = (bf16)lo_[j]; DST_[j+4] = (bf16)hi_[j]; } \
    } while (0)

#define G2_COMPUTE() do { \
    _Pragma("unroll") for (int ks = 0; ks < 2; ++ks) { \
        const int g0 = 8*ks + 2*lq; \
        bf16x8 af[4], bf[4]; \
        _Pragma("unroll") for (int m = 0; m < 4; ++m) { \
            int fr = wr*64 + m*16 + l15; \
            af[m] = Asv[fr*8 + ((ks*4 + lq) ^ (fr & 7))]; \
        } \
        _Pragma("unroll") for (int nn = 0; nn < 4; ++nn) { \
            int fr = wc*64 + nn*16 + l15; \
            G2_CVT8(bf[nn], fr); \
        } \
        _Pragma("unroll") for (int m = 0; m < 4; ++m) \
            _Pragma("unroll") for (int nn = 0; nn < 4; ++nn) \
                acc[m][nn] = __builtin_amdgcn_mfma_f32_16x16x32_bf16(af[m], bf[nn], acc[m][nn], 0, 0, 0); \
    } } while (0)

    G2_STAGE(0);
    for (int kt = 0; kt < KT2; ++kt) {
        __syncthreads();
        G2_COMPUTE();
        if (kt + 1 < KT2) { __syncthreads(); G2_STAGE(kt + 1); }
    }

    #pragma unroll
    for (int m = 0; m < 4; ++m)
        #pragma unroll
        for (int nn = 0; nn < 4; ++nn)
            #pragma unroll
            for (int r = 0; r < 4; ++r) {
                int rl = wr*64 + m*16 + lq*4 + r;
                int grow = r0 + rl;
                if (grow < n) {
                    int idx = base + grow;
                    int tok   = row_token[idx];
                    float wgt = row_wgt[idx];
                    int col = ct*128 + wc*64 + nn*16 + l15;
                    atomicAdd(out + (size_t)tok * K_DIM + col, wgt * acc[m][nn][r]);
                }
            }
#undef G2_STAGE
#undef G2_CVT8
#undef G2_COMPUTE
}

// ---------------------------------------------------------------------------
extern "C" void kernel_launch(void* const* d_in, const int* in_sizes, int n_in,
                              void* d_out, int out_size, void* d_ws, size_t ws_size,
                              hipStream_t stream)
{
    const float* X   = (const float*)d_in[0];
    const float* w1  = (const float*)d_in[1];
    const float* w2  = (const float*)d_in[2];
    const float* tw  = (const float*)d_in[3];
    const int*   ids = (const int*)d_in[4];
    float* out = (float*)d_out;

    // ws layout: act | row_token | row_wgt | counts | offs | Ag | pad
    char* p = (char*)d_ws;
    bf16*  act       = (bf16*)p;   p += (size_t)NROWS * DFF * 2;
    int*   row_token = (int*)p;    p += (size_t)NROWS * 4;
    float* row_wgt   = (float*)p;  p += (size_t)NROWS * 4;
    int*   counts    = (int*)p;    p += 32;
    int*   offs      = (int*)p;    p += 32;
    bf16*  Ag        = (bf16*)p;   p += (size_t)NROWS * K_DIM * 2;
    p += (1u << 20);               // 1 MB pad for benign A-row overreads
    (void)p; (void)ws_size;        // ~33 MB needed; ws >= 162 MB verified

    route_zero_kernel<<<64, 512, 0, stream>>>(ids, tw, counts, offs, row_token,
                                              row_wgt, out, out_size / 4);
    gather_cast_kernel<<<NROWS, 256, 0, stream>>>(X, row_token, Ag);
    gemm1_kernel<<<dim3(DFF/64, NROWS/256, E_NUM), 256, 0, stream>>>(Ag, w1, counts, offs, act);
    gemm2_kernel<<<dim3((K_DIM/128)*KSPLIT, NROWS/128, E_NUM), 256, 0, stream>>>(act, w2, counts, offs, row_token, row_wgt, out);
}